// Round 7
// baseline (1043.308 us; speedup 1.0000x reference)
//
#include <hip/hip_runtime.h>
#include <stdint.h>

// ---------------------------------------------------------------------------
// DeltaNet (gated delta rule) forward, MI355X gfx950. Round 7.
// Round 6 NaN root-caused: phaseB loaded only 1024/4096 floats of M into LDS
// (rows 16..63 uninitialized) AND double-counted the bL diagonal. Both fixed:
//   - each thread loads 4x float4 of M (full 64x64), same for prefetch
//   - acc starts from N only (M = bL*I - Ktilde^T W already has the diagonal)
// Structure (validated round 5 at 842us, phaseB then 347us):
//   phaseA (64x16): gram, T=(I+A)^-1, W(bf16), M=bL*I-K~^T W (fp32),
//                   Uv(bf16), N=K~^T Uv (fp32), cum
//   phaseB (2x16):  S_{c+1} = M_c S_c + N_c, 64 seq chunks, S0 out (bf16)
//   phaseB2 (64x16): U = Uv - W*S0 (parallel, in place)
//   phaseC (64x16): o = e^cum q.S0 + tril(decay qk^T) U, RMSNorm+swish
// P column map: [0,1024) q | [1024,3072) k | [3072,5120) v |
//   [5120,5152) beta-pre | [5152,5168) a-pre | [5168,6192) gate | pad
// ---------------------------------------------------------------------------

typedef unsigned short u16;
typedef __attribute__((ext_vector_type(8))) short bf16x8;
typedef __attribute__((ext_vector_type(4))) float f32x4;

#define TT 2048
#define NP 6208
#define NC 64   // chunks
#define CS 64   // sub-steps per chunk (32 tokens)

__device__ __forceinline__ u16 f2bf(float f) {
  union { float f; uint32_t u; } v; v.f = f;
  uint32_t r = v.u + 0x7fffu + ((v.u >> 16) & 1u);  // RNE
  return (u16)(r >> 16);
}
__device__ __forceinline__ float bf2f(u16 b) {
  union { uint32_t u; float f; } v; v.u = ((uint32_t)b) << 16; return v.f;
}

__global__ void cvt_kernel(const float* __restrict__ src, u16* __restrict__ dst, long n) {
  long i = (long)blockIdx.x * 256 + threadIdx.x;
  if (i < n) dst[i] = f2bf(src[i]);
}

// tiled transpose+convert: dst[n*rows + k] = bf16(src[k*cols + n]); rows%32==0
__global__ __launch_bounds__(256) void transT_kernel(const float* __restrict__ src,
    u16* __restrict__ dst, int rows, int cols) {
  __shared__ float tile[32][33];
  const int tx = threadIdx.x & 31, ty = threadIdx.x >> 5;
  const int c0 = blockIdx.x * 32, r0 = blockIdx.y * 32;
  for (int rr = ty; rr < 32; rr += 8)
    if (c0 + tx < cols) tile[rr][tx] = src[(size_t)(r0 + rr) * cols + c0 + tx];
  __syncthreads();
  for (int rr = ty; rr < 32; rr += 8)
    if (c0 + rr < cols) dst[(size_t)(c0 + rr) * rows + r0 + tx] = f2bf(tile[tx][rr]);
}

__global__ __launch_bounds__(256) void beacon_kernel(float* __restrict__ out, int n) {
  int i = blockIdx.x * 256 + threadIdx.x;
  if (i < n) out[i] = 4000.0f;
}

// C = A[M,K](bf16,lda) * BT[N,K]^T(bf16); out fp32 (Cf) or bf16 (Cb).
__global__ __launch_bounds__(64) void gemm_bt(const u16* __restrict__ A,
                                              const u16* __restrict__ BT,
                                              float* __restrict__ Cf,
                                              u16* __restrict__ Cb,
                                              int K, int lda, int ldc, int out_bf16) {
  const int bm = blockIdx.x * 64, bn = blockIdx.y * 64;
  const int lane = threadIdx.x;
  const int quad = lane >> 4, r = lane & 15;
  f32x4 acc[4][4] = {};
  const u16* ap = A  + (size_t)(bm + r) * lda + quad * 8;
  const u16* bp = BT + (size_t)(bn + r) * K   + quad * 8;
  for (int ks = 0; ks < K; ks += 32) {
    bf16x8 a[4], b[4];
#pragma unroll
    for (int i = 0; i < 4; i++)
      a[i] = *(const bf16x8*)(ap + (size_t)i * 16 * lda + ks);
#pragma unroll
    for (int j = 0; j < 4; j++)
      b[j] = *(const bf16x8*)(bp + (size_t)j * 16 * K + ks);
#pragma unroll
    for (int i = 0; i < 4; i++)
#pragma unroll
      for (int j = 0; j < 4; j++)
        acc[i][j] = __builtin_amdgcn_mfma_f32_16x16x32_bf16(a[i], b[j], acc[i][j], 0, 0, 0);
  }
#pragma unroll
  for (int i = 0; i < 4; i++)
#pragma unroll
    for (int j = 0; j < 4; j++)
#pragma unroll
      for (int rg = 0; rg < 4; rg++) {
        int row = bm + i * 16 + quad * 4 + rg;
        int col = bn + j * 16 + r;
        float v = acc[i][j][rg];
        if (out_bf16) Cb[(size_t)row * ldc + col] = f2bf(v);
        else          Cf[(size_t)row * ldc + col] = v;
      }
}

// l2norm q (x HD^-0.5) and k in place; beta; g (fp32)
__global__ __launch_bounds__(64) void prep_kernel(float* __restrict__ P,
    const float* __restrict__ A_log, const float* __restrict__ dt_bias,
    float* __restrict__ betab, float* __restrict__ gbuf) {
  const int t = blockIdx.x >> 4, h = blockIdx.x & 15, lane = threadIdx.x;
  float* Pt = P + (size_t)t * NP;
  float qv = Pt[h * 64 + lane];
  float ss = qv * qv;
#pragma unroll
  for (int off = 32; off; off >>= 1) ss += __shfl_xor(ss, off);
  Pt[h * 64 + lane] = qv * rsqrtf(ss + 1e-6f) * 0.125f;
#pragma unroll
  for (int nh = 0; nh < 2; nh++) {
    float kv = Pt[1024 + nh * 1024 + h * 64 + lane];
    float ks = kv * kv;
#pragma unroll
    for (int off = 32; off; off >>= 1) ks += __shfl_xor(ks, off);
    Pt[1024 + nh * 1024 + h * 64 + lane] = kv * rsqrtf(ks + 1e-6f);
  }
  if (lane < 2) {
    float bb = Pt[5120 + lane * 16 + h];
    betab[(size_t)(2 * t + lane) * 16 + h] = 2.f / (1.f + expf(-bb));
  }
  if (lane == 0) {
    float a = Pt[5152 + h] + dt_bias[h];
    float sp = (a > 20.f) ? a : log1pf(expf(a));
    gbuf[t * 16 + h] = -expf(A_log[h]) * sp;
  }
}

// phase A: per (chunk c, head h): gram, T=(I+A)^-1, W(bf16), M, Uv(bf16), N, cum
__global__ __launch_bounds__(256) void phaseA_kernel(const float* __restrict__ P,
    const float* __restrict__ betab, const float* __restrict__ gbuf,
    u16* __restrict__ Wbuf, u16* __restrict__ Uvbuf,
    float* __restrict__ Mbuf, float* __restrict__ Nbuf, float* __restrict__ cumbuf) {
  const int c = blockIdx.x, h = blockIdx.y, tid = threadIdx.x;
  __shared__ float kch[64][65], vch[64][65], Ach[64][65], Tch[64][65];
  __shared__ float cumch[64], betach[64], bbch[64], rowfl[64];
  const size_t base = ((size_t)c * 16 + h) * 4096;
  for (int e = tid; e < 4096; e += 256) {
    int i = e >> 6, d = e & 63, s = c * 64 + i, t = s >> 1, nh = s & 1;
    kch[i][d] = P[(size_t)t * NP + 1024 + nh * 1024 + h * 64 + d];
    vch[i][d] = P[(size_t)t * NP + 3072 + nh * 1024 + h * 64 + d];
  }
  if (tid < 64) betach[tid] = betab[(size_t)(c * 64 + tid) * 16 + h];
  __syncthreads();
  if (tid == 0) {
    float cum = 0.f;
    for (int i = 0; i < 64; i++) {
      if ((i & 1) == 0) cum += gbuf[(c * 32 + (i >> 1)) * 16 + h];
      cumch[i] = cum;
    }
  }
  __syncthreads();
  if (tid < 64) {
    bbch[tid] = betach[tid] * expf(cumch[tid]);
    rowfl[tid] = expf(cumch[63] - cumch[tid]);
  }
  // A_{ij} = beta_i * exp(cum_i - cum_j) * (k_i . k_j), j < i
  for (int e = tid; e < 4096; e += 256) {
    int i = e >> 6, j = e & 63;
    float a = 0.f;
    if (j < i) {
      float dot = 0.f;
      for (int d = 0; d < 64; d++) dot += kch[i][d] * kch[j][d];
      a = betach[i] * expf(cumch[i] - cumch[j]) * dot;
    }
    Ach[i][j] = a;
  }
  __syncthreads();
  // T = (I+A)^-1 by forward substitution; 4 lanes per column (same wave)
  {
    int col = tid >> 2, part = tid & 3;
    if (part == 0) Tch[0][col] = (col == 0) ? 1.f : 0.f;
    for (int i = 1; i < 64; i++) {
      float partial = 0.f;
      for (int j = col + part; j < i; j += 4) partial += Ach[i][j] * Tch[j][col];
      partial += __shfl_xor(partial, 1);
      partial += __shfl_xor(partial, 2);
      if (part == 0) Tch[i][col] = ((i == col) ? 1.f : 0.f) - partial;
    }
  }
  __syncthreads();
  // W = T (beta*b .* K) -> Ach (gram dead) + bf16 store
  for (int e = tid; e < 4096; e += 256) {
    int i = e >> 6, d = e & 63;
    float ws = 0.f;
    for (int j = 0; j <= i; j++) ws += Tch[i][j] * bbch[j] * kch[j][d];
    Ach[i][d] = ws;
    Wbuf[base + e] = f2bf(ws);
  }
  __syncthreads();
  // M[m][mm] = bL*delta - sum_i rowf[i]*k[i][m]*W[i][mm]
  {
    float bL = expf(cumch[63]);
    for (int e = tid; e < 4096; e += 256) {
      int m = e >> 6, mm = e & 63;
      float acc = 0.f;
      for (int i = 0; i < 64; i++) acc += rowfl[i] * kch[i][m] * Ach[i][mm];
      Mbuf[base + e] = ((m == mm) ? bL : 0.f) - acc;
    }
  }
  __syncthreads();
  // Uv = T (beta .* V) -> Ach (W dead in LDS) + bf16 store
  for (int e = tid; e < 4096; e += 256) {
    int i = e >> 6, d = e & 63;
    float us = 0.f;
    for (int j = 0; j <= i; j++) us += Tch[i][j] * betach[j] * vch[j][d];
    Ach[i][d] = us;
    Uvbuf[base + e] = f2bf(us);
  }
  __syncthreads();
  // N[m][d] = sum_i rowf[i]*k[i][m]*Uv[i][d]
  for (int e = tid; e < 4096; e += 256) {
    int m = e >> 6, d = e & 63;
    float acc = 0.f;
    for (int i = 0; i < 64; i++) acc += rowfl[i] * kch[i][m] * Ach[i][d];
    Nbuf[base + e] = acc;
  }
  if (tid < 64) cumbuf[((size_t)c * 16 + h) * 64 + tid] = cumch[tid];
}

// phase B: S_{c+1} = M_c S_c + N_c (M includes the bL*I diagonal!), seq over
// chunks; block=(colslice g of 2, head h); writes incoming S0 (bf16)/chunk.
__global__ __launch_bounds__(256) void phaseB_kernel(const float* __restrict__ Mbuf,
    const float* __restrict__ Nbuf, u16* __restrict__ S0buf) {
  const int g = blockIdx.x, h = blockIdx.y, tid = threadIdx.x;
  const int d = tid & 31, mb = (tid >> 5) * 8;
  __shared__ float Sl[64][33];   // scalar access, padded
  __shared__ float Ml[64][64];   // float4-written, unpadded
  __shared__ float Nl[64][32];   // slice, unpadded
  for (int e = tid; e < 64 * 33; e += 256) ((float*)Sl)[e] = 0.f;
  const int nr = tid >> 2, ncol = (tid & 3) * 8;
  // preload chunk 0 (FULL M: 4 float4 per thread = 4096 floats)
  {
    const float4* Mc = (const float4*)(Mbuf + (size_t)h * 4096);
#pragma unroll
    for (int kq = 0; kq < 4; kq++) {
      int f = tid + kq * 256;
      *(float4*)&Ml[f >> 4][(f & 15) * 4] = Mc[f];
    }
    const float* Nc = Nbuf + (size_t)h * 4096;
    *(float4*)&Nl[nr][ncol]     = *(const float4*)(Nc + nr * 64 + g * 32 + ncol);
    *(float4*)&Nl[nr][ncol + 4] = *(const float4*)(Nc + nr * 64 + g * 32 + ncol + 4);
  }
  __syncthreads();
  for (int c = 0; c < NC; c++) {
    const size_t base = (size_t)c * 16 + h;
    float4 pm[4], pn0, pn1;
    if (c + 1 < NC) {   // prefetch next chunk (overlaps compute via vmcnt)
      const float4* Mn = (const float4*)(Mbuf + ((size_t)(c + 1) * 16 + h) * 4096);
#pragma unroll
      for (int kq = 0; kq < 4; kq++) pm[kq] = Mn[tid + kq * 256];
      const float* Nn = Nbuf + ((size_t)(c + 1) * 16 + h) * 4096;
      pn0 = *(const float4*)(Nn + nr * 64 + g * 32 + ncol);
      pn1 = *(const float4*)(Nn + nr * 64 + g * 32 + ncol + 4);
    }
    float acc[8];
#pragma unroll
    for (int j = 0; j < 8; j++) {
      float sv = Sl[mb + j][d];
      S0buf[base * 4096 + (mb + j) * 64 + g * 32 + d] = f2bf(sv);  // incoming S
      acc[j] = Nl[mb + j][d];          // M already carries bL on the diagonal
    }
    for (int mm = 0; mm < 64; mm++) {
      float s = Sl[mm][d];
#pragma unroll
      for (int j = 0; j < 8; j++) acc[j] += Ml[mb + j][mm] * s;
    }
    __syncthreads();
#pragma unroll
    for (int j = 0; j < 8; j++) Sl[mb + j][d] = acc[j];
    if (c + 1 < NC) {
#pragma unroll
      for (int kq = 0; kq < 4; kq++) {
        int f = tid + kq * 256;
        *(float4*)&Ml[f >> 4][(f & 15) * 4] = pm[kq];
      }
      *(float4*)&Nl[nr][ncol] = pn0;
      *(float4*)&Nl[nr][ncol + 4] = pn1;
    }
    __syncthreads();
  }
}

// phase B2 (parallel): U = Uv - W*S0, in place over Uvbuf
__global__ __launch_bounds__(256) void phaseB2_kernel(const u16* __restrict__ Wbuf,
    const u16* __restrict__ S0buf, u16* __restrict__ Uvbuf) {
  const int c = blockIdx.x, h = blockIdx.y, tid = threadIdx.x;
  const int d = tid & 63, iw = tid >> 6;
  __shared__ float Wl[64][65], S0l[64][65];
  const size_t base = ((size_t)c * 16 + h) * 4096;
  for (int e = tid; e < 4096; e += 256) {
    Wl[e >> 6][e & 63] = bf2f(Wbuf[base + e]);
    S0l[e >> 6][e & 63] = bf2f(S0buf[base + e]);
  }
  __syncthreads();
  float acc[16];
#pragma unroll
  for (int j = 0; j < 16; j++) acc[j] = 0.f;
  for (int m = 0; m < 64; m++) {
    float s = S0l[m][d];
#pragma unroll
    for (int j = 0; j < 16; j++) acc[j] += Wl[iw * 16 + j][m] * s;
  }
#pragma unroll
  for (int j = 0; j < 16; j++) {
    int i = iw * 16 + j;
    float uv = bf2f(Uvbuf[base + i * 64 + d]);
    Uvbuf[base + i * 64 + d] = f2bf(uv - acc[j]);
  }
}

// phase C: o = e^cum q.S0 + tril(decay * qk^T) U, fused RMSNorm+swish -> ybuf
__global__ __launch_bounds__(256) void phaseC_kernel(const float* __restrict__ P,
    const float* __restrict__ cumbuf, const u16* __restrict__ Ubuf,
    const u16* __restrict__ S0buf, const float* __restrict__ nw,
    u16* __restrict__ ybuf) {
  const int c = blockIdx.x, h = blockIdx.y, tid = threadIdx.x;
  __shared__ float A1[64][65];   // k, then S0
  __shared__ float Ull[64][65];
  __shared__ float ql[32][65], Pm[32][65];
  __shared__ float cuml[64], nwl[64];
  const size_t base = (size_t)c * 16 + h;
  for (int e = tid; e < 4096; e += 256) {
    int i = e >> 6, d = e & 63, s = c * 64 + i, t = s >> 1, nh = s & 1;
    A1[i][d] = P[(size_t)t * NP + 1024 + nh * 1024 + h * 64 + d];  // k
    Ull[i][d] = bf2f(Ubuf[base * 4096 + e]);
  }
  for (int e = tid; e < 2048; e += 256) {
    int r = e >> 6, d = e & 63;
    ql[r][d] = P[(size_t)(c * 32 + r) * NP + h * 64 + d];
  }
  if (tid < 64) { cuml[tid] = cumbuf[base * 64 + tid]; nwl[tid] = nw[tid]; }
  __syncthreads();
  // Pm[r][j] = exp(cum_{2r+1}-cum_j) * (q_r . k_j), j <= 2r+1
  for (int e = tid; e < 2048; e += 256) {
    int r = e >> 6, j = e & 63, i = 2 * r + 1;
    float pv = 0.f;
    if (j <= i) {
      float dot = 0.f;
      for (int d = 0; d < 64; d++) dot += ql[r][d] * A1[j][d];
      pv = expf(cuml[i] - cuml[j]) * dot;
    }
    Pm[r][j] = pv;
  }
  __syncthreads();
  for (int e = tid; e < 4096; e += 256)   // restage S0 over k
    A1[e >> 6][e & 63] = bf2f(S0buf[base * 4096 + e]);
  __syncthreads();
  for (int e = tid; e < 2048; e += 256) {
    int r = e >> 6, d = e & 63, i = 2 * r + 1;
    float acc = 0.f;
    for (int m = 0; m < 64; m++) acc += ql[r][m] * A1[m][d];
    acc *= expf(cuml[i]);
    float acc2 = 0.f;
    for (int j = 0; j <= i; j++) acc2 += Pm[r][j] * Ull[j][d];
    float o = acc + acc2;
    float ss = o * o;                     // wave: r uniform, d = lane
#pragma unroll
    for (int off = 32; off; off >>= 1) ss += __shfl_xor(ss, off);
    float on = o * rsqrtf(ss * (1.f / 64.f) + 1e-5f) * nwl[d];
    int t = c * 32 + r;
    float gt = P[(size_t)t * NP + 5168 + h * 64 + d];
    float sw = gt / (1.f + expf(-gt));
    ybuf[(size_t)t * 1024 + h * 64 + d] = f2bf(on * sw);
  }
}

extern "C" void kernel_launch(void* const* d_in, const int* in_sizes, int n_in,
                              void* d_out, int out_size, void* d_ws, size_t ws_size,
                              hipStream_t stream) {
  const float* x       = (const float*)d_in[0];
  const float* Wq      = (const float*)d_in[1];
  const float* Wk      = (const float*)d_in[2];
  const float* Wv      = (const float*)d_in[3];
  const float* Wb      = (const float*)d_in[4];
  const float* Wa      = (const float*)d_in[5];
  const float* A_log   = (const float*)d_in[6];
  const float* dt_bias = (const float*)d_in[7];
  const float* Wg      = (const float*)d_in[8];
  const float* nw      = (const float*)d_in[9];
  const float* Wo      = (const float*)d_in[10];
  float* out = (float*)d_out;

  char* w = (char*)d_ws;
  size_t used = 0;
  auto alloc = [&](size_t bytes) {
    char* p = w + used; used += (bytes + 255) & ~(size_t)255; return p;
  };
  u16*   xb    = (u16*)  alloc(2048UL * 1024 * 2);
  u16*   WT    = (u16*)  alloc((size_t)NP * 1024 * 2);
  u16*   WoT   = (u16*)  alloc(1024UL * 1024 * 2);
  float* P     = (float*)alloc(2048UL * NP * 4);
  float* betab = (float*)alloc(4096UL * 16 * 4);
  float* gbuf  = (float*)alloc(2048UL * 16 * 4);
  u16*   ybuf  = (u16*)  alloc(2048UL * 1024 * 2);
  u16*   Wbuf  = (u16*)  alloc((size_t)NC * 16 * 4096 * 2);
  u16*   Uvbuf = (u16*)  alloc((size_t)NC * 16 * 4096 * 2);
  u16*   S0buf = (u16*)  alloc((size_t)NC * 16 * 4096 * 2);
  float* Mbuf  = (float*)alloc((size_t)NC * 16 * 4096 * 4);
  float* Nbuf  = (float*)alloc((size_t)NC * 16 * 4096 * 4);
  float* cumb  = (float*)alloc((size_t)NC * 16 * 64 * 4);

  auto tgrid = [](long n) { return dim3((unsigned)((n + 255) / 256)); };
  if (used > ws_size) {  // deterministic guard: workspace too small
    beacon_kernel<<<tgrid(out_size), 256, 0, stream>>>(out, out_size);
    return;
  }

  hipMemsetAsync(WT + 6192UL * 1024, 0, 16UL * 1024 * 2, stream);

  cvt_kernel<<<tgrid(2048L*1024), 256, 0, stream>>>(x, xb, 2048L * 1024);
  auto trgrid = [](int cols) { return dim3((unsigned)((cols + 31) / 32), 32); };
  transT_kernel<<<trgrid(1024), 256, 0, stream>>>(Wq, WT + 0L,         1024, 1024);
  transT_kernel<<<trgrid(2048), 256, 0, stream>>>(Wk, WT + 1024L*1024, 1024, 2048);
  transT_kernel<<<trgrid(2048), 256, 0, stream>>>(Wv, WT + 3072L*1024, 1024, 2048);
  transT_kernel<<<trgrid(32),   256, 0, stream>>>(Wb, WT + 5120L*1024, 1024, 32);
  transT_kernel<<<trgrid(16),   256, 0, stream>>>(Wa, WT + 5152L*1024, 1024, 16);
  transT_kernel<<<trgrid(1024), 256, 0, stream>>>(Wg, WT + 5168L*1024, 1024, 1024);
  transT_kernel<<<trgrid(1024), 256, 0, stream>>>(Wo, WoT,             1024, 1024);

  gemm_bt<<<dim3(32, 97), 64, 0, stream>>>(xb, WT, P, nullptr, 1024, 1024, NP, 0);
  prep_kernel<<<dim3(2048 * 16), 64, 0, stream>>>(P, A_log, dt_bias, betab, gbuf);

  phaseA_kernel<<<dim3(NC, 16), 256, 0, stream>>>(P, betab, gbuf, Wbuf, Uvbuf, Mbuf, Nbuf, cumb);
  phaseB_kernel<<<dim3(2, 16),  256, 0, stream>>>(Mbuf, Nbuf, S0buf);
  phaseB2_kernel<<<dim3(NC, 16), 256, 0, stream>>>(Wbuf, S0buf, Uvbuf);
  phaseC_kernel<<<dim3(NC, 16), 256, 0, stream>>>(P, cumb, Uvbuf, S0buf, nw, ybuf);

  gemm_bt<<<dim3(32, 16), 64, 0, stream>>>(ybuf, WoT, out, nullptr, 1024, 1024, 1024, 0);
}